// Round 6
// baseline (625.609 us; speedup 1.0000x reference)
//
#include <hip/hip_runtime.h>
#include <math.h>

#define BATCH 32
#define NN 1024
#define MM 1024
#define LPATH (NN + MM - 1)     // 2047

// ---------------- Persistent wavefront-panel geometry ----------------
// 8x8 grid of 128x128 panels per batch. Block = (batch, band r): one wave,
// owns rows 128r..128r+127 (lane: rows 2l, 2l+1), processes its 8 panels
// c=0..7 sequentially. Right-column boundary stays in registers across
// panels; bottom row crosses to band r+1 via global memory + flag handshake.
#define PB 128                  // panel rows
#define PQ 128                  // panel cols
#define GB 8                    // bands
#define GH 8                    // panel columns
#define PAN_WORDS 1536          // 24 sblk x 64 lanes (4 bits/step/lane)
#define BAT_WORDS (GB * GH * PAN_WORDS)               // 98304 words / batch
#define DEC_WORDS ((size_t)BATCH * BAT_WORDS)         // 3,145,728 words
#define BR_OFFW DEC_WORDS                             // brow planes (9x1024/b)
#define BRPL (9 * 1024)
#define FL_OFFW (BR_OFFW + (size_t)BATCH * BRPL)      // flags (8x8/b)
#define WS_WORDS (FL_OFFW + (size_t)BATCH * 64)
#define REQ_WS_NEW (WS_WORDS * 4)                     // ~13.8 MB

// Legacy (proven 557us) path requirement
#define DEC_WORDS_PER_BATCH ((NN / 4) * (MM / 4))     // 65536
#define REQ_WS ((size_t)BATCH * DEC_WORDS_PER_BATCH * 4)   // 8 MB

__global__ void init_kernel(float* out) { out[0] = 0.0f; }

// ---- init for persistent path: zero flags + out (runs each graph replay) ---
__global__ void init3(unsigned* __restrict__ wsu, float* __restrict__ out)
{
    const int t = threadIdx.x;
    if (t == 0) out[0] = 0.0f;
    for (int i = t; i < BATCH * 64; i += 256) wsu[FL_OFFW + i] = 0u;
}

__device__ __forceinline__ float wave_shr1(float v)
{
    return __int_as_float(__builtin_amdgcn_update_dpp(
        __float_as_int(v), __float_as_int(v), 0x138, 0xF, 0xF, false));
}

// ---- Persistent DP kernel: 256 blocks (32 batches x 8 bands) x 64 threads ---
// Inner 8-step loop copied verbatim from the R5-verified panel kernel
// (absmax=0); only boundary plumbing differs:
//  - left column / diag seed: carried in D0,D1 registers across panels
//  - top row: brow plane r (global), read with agent-scope atomic loads after
//    an acquire spin on flag[b][r-1][c]; r==0 uses INF constants
//  - bottom row: published to plane r+1 with agent-scope atomic stores, then
//    release-store of flag[b][r][c] (r<7)
// Deadlock-safety: producer block (b,r-1) has lower blockIdx than consumer
// (b,r); 256 one-wave blocks are co-resident on 256 CUs.
__global__ __launch_bounds__(64, 1) void dtw_dp(
    const float* __restrict__ preds, const float* __restrict__ targs,
    unsigned* __restrict__ wsu)
{
    const int blk = blockIdx.x;
    const int b = blk >> 3, r = blk & 7;
    const int l = threadIdx.x;
    const float INF = __builtin_inff();

    __shared__ __align__(16) float txA[1160], tyA[1160];  // skew-padded stream
    __shared__ __align__(16) float TL[208];               // top row + INF pads
    __shared__ __align__(16) float botL[128];

    // pads
    for (int i = l; i < 64; i += 64) { txA[i] = 0.f; tyA[i] = 0.f; }
    for (int i = 1087 + l; i < 1160; i += 64) { txA[i] = 0.f; tyA[i] = 0.f; }
    if (l < 16) TL[192 + l] = INF;
    TL[128 + l] = INF;
    if (r == 0) { TL[l] = INF; TL[64 + l] = INF; }   // band 0: row -1 == INF

    // stage full targ stream once (cols 0..1023 at txA[63+j])
    {
        const float4* tg4 = (const float4*)targs + (size_t)b * MM;
        #pragma unroll
        for (int k = 0; k < 4; ++k) {
            const float4 v = tg4[k * 64 + l];
            const int j = 63 + 4 * (k * 64 + l);
            txA[j] = v.x; tyA[j] = v.y;
            // only features 0,1 (basis x,y) are used
            const float4 w = tg4[k * 64 + l];   // same load, elements 2,3 unused
            (void)w;
        }
    }
    // NOTE: above wrote only element 0 of each float4 row -- fix: write all 4
    // rows per float4? targs rows are (M,4): one float4 == ONE col's features.
    // So col j's (x,y) = tg4[j].x, tg4[j].y. Stage 16 cols per lane:
    {
        const float4* tg4 = (const float4*)targs + (size_t)b * MM;
        for (int j = l; j < MM; j += 64) {
            const float4 v = tg4[j];
            txA[63 + j] = v.x; tyA[63 + j] = v.y;
        }
    }

    // pred rows (2 per lane), registers for the whole band
    const float4* pp4 = (const float4*)preds + (size_t)b * NN + r * PB;
    const float4 p0 = pp4[2 * l], p1 = pp4[2 * l + 1];
    const float px0 = p0.x, py0 = p0.y, px1 = p1.x, py1 = p1.y;

    unsigned* __restrict__ browI = wsu + BR_OFFW + (size_t)b * BRPL;
    unsigned* __restrict__ flagB = wsu + FL_OFFW + (size_t)b * 64;

    float D0 = INF, D1 = INF;      // running left-column boundary (col -1)
    __syncthreads();               // LDS staging visible (single wave, cheap)

    for (int c = 0; c < GH; ++c) {
        // ---- acquire top boundary ----
        float tlm1;
        if (r > 0) {
            const int fi = (r - 1) * 8 + c;
            while (__hip_atomic_load(&flagB[fi], __ATOMIC_ACQUIRE,
                                     __HIP_MEMORY_SCOPE_AGENT) == 0u)
                __builtin_amdgcn_s_sleep(1);
            const unsigned* bp = browI + (size_t)r * 1024 + c * PQ;
            TL[2 * l] = __int_as_float(__hip_atomic_load(
                (unsigned*)&bp[2 * l], __ATOMIC_RELAXED, __HIP_MEMORY_SCOPE_AGENT));
            TL[2 * l + 1] = __int_as_float(__hip_atomic_load(
                (unsigned*)&bp[2 * l + 1], __ATOMIC_RELAXED, __HIP_MEMORY_SCOPE_AGENT));
            tlm1 = (c == 0) ? INF
                 : __int_as_float(__hip_atomic_load((unsigned*)&bp[-1],
                       __ATOMIC_RELAXED, __HIP_MEMORY_SCOPE_AGENT));
        } else {
            tlm1 = (c == 0) ? 0.0f : INF;
        }
        // diag seed for this panel: D(2l-1, 128c-1)
        const float sh1 = wave_shr1(D1);
        const float dg0init = (l == 0) ? tlm1 : ((c == 0) ? INF : sh1);

        unsigned* __restrict__ decP = wsu + (size_t)b * BAT_WORDS
                                    + (size_t)(r * GH + c) * PAN_WORDS + l;
        const int cb = 63 + c * PQ;     // LDS base for this panel's cols

        // tx/ty register ring init (steps s=0..3 of this panel)
        float txb[8], tyb[8];
        #pragma unroll
        for (int k = 0; k < 4; ++k) {
            txb[k] = txA[cb + k - l]; tyb[k] = tyA[cb + k - l];
        }
        float up0prev = INF;

        for (int it = 0; it < 24; ++it) {
            const int s0 = it * 8;
            const float4 T4a = *(const float4*)&TL[s0];
            const float4 T4b = *(const float4*)&TL[s0 + 4];
            const float Tv[8] = {T4a.x, T4a.y, T4a.z, T4a.w,
                                 T4b.x, T4b.y, T4b.z, T4b.w};
            unsigned word = 0;
            #pragma unroll
            for (int k = 0; k < 8; ++k) {
                const int s = s0 + k;
                const int jq = s - l;
                txb[(k + 4) & 7] = txA[cb + jq + 4];
                tyb[(k + 4) & 7] = tyA[cb + jq + 4];
                const float sh = wave_shr1(D1);
                const float up0 = (l == 0) ? Tv[k] : sh;
                const float dg0 = (jq == 0) ? dg0init : up0prev;
                const float tx = txb[k], ty = tyb[k];
                const float dx0 = px0 - tx, dy0 = py0 - ty;
                const float c0 = __builtin_amdgcn_sqrtf(dx0 * dx0 + dy0 * dy0);
                const float mn0 = fminf(dg0, fminf(up0, D0));
                const float D0n = c0 + mn0;
                const unsigned m0 = (mn0 == dg0) ? 0u : ((mn0 == up0) ? 1u : 2u);
                const float dg1 = D0;
                const float dx1 = px1 - tx, dy1 = py1 - ty;
                const float c1 = __builtin_amdgcn_sqrtf(dx1 * dx1 + dy1 * dy1);
                const float mn1 = fminf(dg1, fminf(D0n, D1));
                const float D1n = c1 + mn1;
                const unsigned m1 = (mn1 == dg1) ? 0u : ((mn1 == D0n) ? 1u : 2u);
                word |= (m0 | (m1 << 2)) << (4 * k);
                const bool act = (jq >= 0) && (jq < PQ);
                if (act) { D0 = D0n; D1 = D1n; }
                up0prev = up0;
                if (l == 63 && act) botL[jq] = D1n;
            }
            decP[it * 64] = word;
        }

        // ---- publish bottom row (plane r+1) ----
        if (r < GB - 1) {
            unsigned* bw = browI + (size_t)(r + 1) * 1024 + c * PQ;
            __hip_atomic_store(&bw[2 * l], __float_as_int(botL[2 * l]),
                               __ATOMIC_RELAXED, __HIP_MEMORY_SCOPE_AGENT);
            __hip_atomic_store(&bw[2 * l + 1], __float_as_int(botL[2 * l + 1]),
                               __ATOMIC_RELAXED, __HIP_MEMORY_SCOPE_AGENT);
            __threadfence();
            if (l == 0)
                __hip_atomic_store(&flagB[r * 8 + c], 1u, __ATOMIC_RELEASE,
                                   __HIP_MEMORY_SCOPE_AGENT);
        }
    }
}

// ---- Backtrack + loss: 32 blocks x 256 threads (R5 verbatim, 157us) --------
__global__ __launch_bounds__(256, 1) void dtw_bt(
    const float* __restrict__ preds, const float* __restrict__ targs,
    const float* __restrict__ subcoef, const float* __restrict__ ws,
    float* __restrict__ out)
{
    const int b = blockIdx.x, t = threadIdx.x;
    __shared__ float pxA[NN], pyA[NN], txA[MM], tyA[MM];   // 16 KB
    __shared__ unsigned path[2048];                        // 8 KB
    __shared__ int sN;
    __shared__ float wsum[4];

    for (int it = 0; it < 4; ++it) {
        const int idx = it * 256 + t;
        const float4 p4 = ((const float4*)preds)[(size_t)b * NN + idx];
        pxA[idx] = p4.x; pyA[idx] = p4.y;
        const float4 t4 = ((const float4*)targs)[(size_t)b * MM + idx];
        txA[idx] = t4.x; tyA[idx] = t4.y;
    }
    __syncthreads();

    if (t == 0) {
        const unsigned* __restrict__ decB =
            (const unsigned*)ws + (size_t)b * BAT_WORDS;
        int i = NN - 1, j = MM - 1, n = 0;
        int cwidx = -1; unsigned cw = 0;
        while (true) {
            path[n++] = ((unsigned)i << 16) | (unsigned)j;
            if ((i | j) == 0) break;
            const int ll = (i & 127) >> 1;
            const int ss = ll + (j & 127);
            const int widx = (((i >> 7) << 3) + (j >> 7)) * PAN_WORDS
                           + (ss >> 3) * 64 + ll;
            if (widx != cwidx) { cw = decB[widx]; cwidx = widx; }
            const unsigned m = (cw >> ((ss & 7) * 4 + (i & 1) * 2)) & 3u;
            i -= (m != 2u); j -= (m != 1u);
        }
        sN = n;
    }
    __syncthreads();

    const float sc0 = subcoef[0], sc1 = subcoef[1];
    const int n = sN;
    float acc = 0.0f;
    for (int p = t; p < n; p += 256) {
        const unsigned e = path[p];
        const int i = (int)(e >> 16), j = (int)(e & 0xffffu);
        acc += fabsf(pxA[i] - txA[j]) * sc0 + fabsf(pyA[i] - tyA[j]) * sc1;
    }
    #pragma unroll
    for (int o = 32; o > 0; o >>= 1) acc += __shfl_down(acc, o);
    if ((t & 63) == 0) wsum[t >> 6] = acc;
    __syncthreads();
    if (t == 0) atomicAdd(out, (wsum[0] + wsum[1]) + (wsum[2] + wsum[3]));
}

// =================== Legacy proven path (557us, needs 8MB) ===================
__device__ inline void bt_walk4(const unsigned* __restrict__ sdec, int roff,
                                int iLow, int& i, int& j, int& n,
                                unsigned* __restrict__ path)
{
    int ri = i >> 2, jc = j >> 2;
    unsigned w = sdec[(ri - roff) * 256 + jc];
    while (true) {
        const int base = (ri - roff) * 256 + jc;
        const unsigned wl = sdec[(jc > 0)    ? base - 1   : base];
        const unsigned wu = sdec[(ri > roff) ? base - 256 : base];
        const unsigned wd = sdec[(ri > roff && jc > 0) ? base - 257 : base];
        bool done = false, susp = false;
        while (true) {
            path[n++] = ((unsigned)i << 16) | (unsigned)j;
            if ((i | j) == 0) { done = true; break; }
            const unsigned m = (w >> (((i & 3) * 4 + (j & 3)) * 2)) & 3u;
            i -= (m != 2u); j -= (m != 1u);
            if (i < iLow) { susp = true; break; }
            if ((i >> 2) != ri || (j >> 2) != jc) break;
        }
        if (done || susp) break;
        const int nri = i >> 2, njc = j >> 2;
        w = (nri == ri) ? wl : ((njc == jc) ? wu : wd);
        ri = nri; jc = njc;
    }
}

#define RRL 4
#define CCL 4
#define LANES 64
#define NWAVE 4
#define TPBL (MM / 4)
#define NSUP (TPBL + LANES - 1)
#define LAG 72
#define TOTL (NSUP + (NWAVE - 1) * LAG)
#define DEPTH 32

__global__ __launch_bounds__(256, 1) void dtw_fused_legacy(
    const float* __restrict__ preds, const float* __restrict__ targs,
    const float* __restrict__ subcoef, unsigned* __restrict__ dec,
    float* __restrict__ out)
{
    const int b = blockIdx.x, t = threadIdx.x;
    const int l = t & 63, w = t >> 6;
    const float INF = __builtin_inff();

    __shared__ float pxA[NN], pyA[NN], txA[MM], tyA[MM];
    __shared__ float4 ring[NWAVE - 1][DEPTH];
    __shared__ unsigned sdec[128 * 256];
    __shared__ unsigned path[LPATH + 1];
    __shared__ int sI, sJ, sN;
    __shared__ float wsum[NWAVE];

    for (int it = 0; it < NN / 256; ++it) {
        const int idx = it * 256 + t;
        const float4 p4 = ((const float4*)preds)[(size_t)b * NN + idx];
        pxA[idx] = p4.x; pyA[idx] = p4.y;
        const float4 t4 = ((const float4*)targs)[(size_t)b * MM + idx];
        txA[idx] = t4.x; tyA[idx] = t4.y;
    }
    __syncthreads();

    const int i0 = (w << 8) + (l << 2);
    const float4 px4 = ((const float4*)pxA)[i0 >> 2];
    const float4 py4 = ((const float4*)pyA)[i0 >> 2];
    const float px[RRL] = {px4.x, px4.y, px4.z, px4.w};
    const float py[RRL] = {py4.x, py4.y, py4.z, py4.w};
    unsigned* __restrict__ decW =
        dec + (size_t)b * DEC_WORDS_PER_BATCH + ((size_t)w << 14) + (size_t)l;

    float Dp[RRL], Dbot[CCL], bv[CCL];
    #pragma unroll
    for (int r = 0; r < RRL; ++r) Dp[r] = INF;
    #pragma unroll
    for (int c = 0; c < CCL; ++c) { Dbot[c] = INF; bv[c] = INF; }
    float bndRet = (w == 0 && l == 0) ? 0.0f : INF;
    float4 gcur = make_float4(INF, INF, INF, INF);
    float4 tx4 = ((const float4*)txA)[0], ty4 = ((const float4*)tyA)[0];
    const float4* __restrict__ ringR = ring[(w > 0) ? (w - 1) : 0];

    for (int u = 0; u < TOTL; ++u) {
        const int ul = u - LAG * w;
        if (l == 0) {
            const bool gb = (w > 0) && (ul >= 0) && (ul < TPBL);
            bv[0] = gb ? gcur.x : INF; bv[1] = gb ? gcur.y : INF;
            bv[2] = gb ? gcur.z : INF; bv[3] = gb ? gcur.w : INF;
        }
        const bool act = (ul >= l) && (ul < l + TPBL);
        if (act) {
            const float cx[CCL] = {tx4.x, tx4.y, tx4.z, tx4.w};
            const float cy[CCL] = {ty4.x, ty4.y, ty4.z, ty4.w};
            float cost[RRL][CCL];
            #pragma unroll
            for (int c = 0; c < CCL; ++c)
                #pragma unroll
                for (int r = 0; r < RRL; ++r) {
                    const float dx = px[r] - cx[c], dy = py[r] - cy[c];
                    cost[r][c] = __builtin_amdgcn_sqrtf(dx * dx + dy * dy);
                }
            unsigned word = 0;
            #pragma unroll
            for (int c = 0; c < CCL; ++c) {
                float up = bv[c];
                float dg = (c == 0) ? bndRet : bv[c - 1];
                #pragma unroll
                for (int r = 0; r < RRL; ++r) {
                    const float lf = Dp[r];
                    const unsigned m = (dg <= up && dg <= lf) ? 0u
                                     : ((up <= lf) ? 1u : 2u);
                    const float D = cost[r][c] + fminf(dg, fminf(up, lf));
                    word |= m << ((r * 4 + c) * 2);
                    dg = lf; up = D; Dp[r] = D;
                }
                Dbot[c] = up;
            }
            decW[(ul & 255) << 6] = word;
            if (l == LANES - 1 && w < NWAVE - 1)
                ring[w][ul & (DEPTH - 1)] =
                    make_float4(Dbot[0], Dbot[1], Dbot[2], Dbot[3]);
        }
        bndRet = bv[CCL - 1];
        #pragma unroll
        for (int c = 0; c < CCL; ++c) bv[c] = __shfl_up(Dbot[c], 1);
        const int un = ul + 1;
        if (un >= l && un < l + TPBL) {
            const int jn = CCL * (un - l);
            tx4 = ((const float4*)txA)[jn >> 2];
            ty4 = ((const float4*)tyA)[jn >> 2];
        }
        if (w > 0 && un >= 0 && un < TPBL)
            gcur = ringR[(un + 63) & (DEPTH - 1)];
        if ((u & 7) == 7) __syncthreads();
    }

    __threadfence_block();
    __syncthreads();

    const unsigned* __restrict__ decB = dec + (size_t)b * DEC_WORDS_PER_BATCH;
    {
        const uint4* g4 = (const uint4*)(decB + 32768);
        for (int k = t; k < 8192; k += 256) {
            const uint4 v = g4[k];
            const int kb = k << 2;
            const int wv = kb >> 14;
            const int rem = kb & 16383;
            const int q = rem >> 6;
            const int lb = rem & 63;
            const unsigned wd[4] = {v.x, v.y, v.z, v.w};
            #pragma unroll
            for (int e = 0; e < 4; ++e) {
                const int ll = lb + e;
                const int row = (wv << 6) + ll;
                const int jc = (q - ll) & 255;
                sdec[(row << 8) + jc] = wd[e];
            }
        }
    }
    __syncthreads();
    if (t == 0) {
        int i = NN - 1, j = MM - 1, n = 0;
        bt_walk4(sdec, 128, 512, i, j, n, path);
        sI = i; sJ = j; sN = n;
    }
    __syncthreads();
    {
        const uint4* g4 = (const uint4*)decB;
        for (int k = t; k < 8192; k += 256) {
            const uint4 v = g4[k];
            const int kb = k << 2;
            const int wv = kb >> 14;
            const int rem = kb & 16383;
            const int q = rem >> 6;
            const int lb = rem & 63;
            const unsigned wd[4] = {v.x, v.y, v.z, v.w};
            #pragma unroll
            for (int e = 0; e < 4; ++e) {
                const int ll = lb + e;
                const int row = (wv << 6) + ll;
                const int jc = (q - ll) & 255;
                sdec[(row << 8) + jc] = wd[e];
            }
        }
    }
    __syncthreads();
    if (t == 0) {
        int i = sI, j = sJ, n = sN;
        bt_walk4(sdec, 0, 0, i, j, n, path);
        sN = n;
    }
    __syncthreads();

    const float sc0 = subcoef[0], sc1 = subcoef[1];
    const int n = sN;
    float acc = 0.0f;
    for (int p = t; p < n; p += 256) {
        const unsigned e = path[p];
        const int i = (int)(e >> 16), j = (int)(e & 0xffffu);
        acc += fabsf(pxA[i] - txA[j]) * sc0 + fabsf(pyA[i] - tyA[j]) * sc1;
    }
    #pragma unroll
    for (int o = 32; o > 0; o >>= 1) acc += __shfl_down(acc, o);
    if ((t & 63) == 0) wsum[t >> 6] = acc;
    __syncthreads();
    if (t == 0) atomicAdd(out, (wsum[0] + wsum[1]) + (wsum[2] + wsum[3]));
}

// ------------- Fallback (only if ws too small for everything) ----------------
__global__ __launch_bounds__(256) void dtw_fallback(
    const float* __restrict__ preds, const float* __restrict__ targs,
    const float* __restrict__ subcoef, unsigned* __restrict__ dec,
    float* __restrict__ out)
{
    const int b = blockIdx.x;
    const int t = threadIdx.x;
    const float INF = __builtin_inff();
    __shared__ float px[NN], py[NN];
    __shared__ float txy[2 * MM];
    __shared__ float bbuf[2][256];

    for (int it = 0; it < NN / 256; ++it) {
        const int idx = it * 256 + t;
        const float4 p4 = ((const float4*)preds)[(size_t)b * NN + idx];
        px[idx] = p4.x; py[idx] = p4.y;
        const float4 t4 = ((const float4*)targs)[(size_t)b * MM + idx];
        txy[2 * idx] = t4.x; txy[2 * idx + 1] = t4.y;
    }
    bbuf[0][t] = INF; bbuf[1][t] = INF;
    __syncthreads();

    float pxr[4], pyr[4], Dp[4];
    #pragma unroll
    for (int r = 0; r < 4; ++r) {
        pxr[r] = px[4 * t + r]; pyr[r] = py[4 * t + r]; Dp[r] = INF;
    }
    float dgB = (t == 0) ? 0.0f : INF;
    unsigned packed = 0;
    unsigned* decB = dec + (size_t)b * 65536;
    for (int s = 0; s < MM + 255; ++s) {
        const int j = s - t;
        const float upB = (t == 0) ? INF : bbuf[(s + 1) & 1][t - 1];
        if (j >= 0 && j < MM) {
            const float txj = txy[2 * j], tyj = txy[2 * j + 1];
            float up = upB, dg = dgB;
            unsigned mbits = 0;
            #pragma unroll
            for (int r = 0; r < 4; ++r) {
                const float dx = pxr[r] - txj, dy = pyr[r] - tyj;
                const float c = sqrtf(dx * dx + dy * dy);
                const float lf = Dp[r];
                const unsigned m = (dg <= up && dg <= lf) ? 0u
                                 : ((up <= lf) ? 1u : 2u);
                mbits |= m << (r * 8 + (j & 3) * 2);
                const float Dc = c + fminf(up, fminf(dg, lf));
                dg = lf; up = Dc; Dp[r] = Dc;
            }
            packed |= mbits;
            if ((j & 3) == 3) { decB[(unsigned)t * 256 + (j >> 2)] = packed; packed = 0; }
            bbuf[s & 1][t] = Dp[3];
        }
        dgB = upB;
        __syncthreads();
    }
    __threadfence_block();
    __syncthreads();
    if (t == 0) {
        const float sc0 = subcoef[0], sc1 = subcoef[1];
        int i = NN - 1, jj = MM - 1;
        float loss = 0.0f;
        int ti = i >> 2, tj = jj >> 2;
        unsigned wv = decB[ti * 256 + tj];
        while (true) {
            const int tjl = (tj > 0) ? tj - 1 : 0;
            const int til = (ti > 0) ? ti - 1 : 0;
            const unsigned wl = decB[ti * 256 + tjl];
            const unsigned wu = decB[til * 256 + tj];
            const unsigned wd = decB[til * 256 + tjl];
            bool done = false;
            while (true) {
                loss += fabsf(px[i] - txy[2 * jj]) * sc0
                      + fabsf(py[i] - txy[2 * jj + 1]) * sc1;
                if ((i | jj) == 0) { done = true; break; }
                const unsigned m = (wv >> (((i & 3) * 4 + (jj & 3)) * 2)) & 3u;
                i -= (m != 2u); jj -= (m != 1u);
                if ((i >> 2) != ti || (jj >> 2) != tj) break;
            }
            if (done) break;
            const int nti = i >> 2, ntj = jj >> 2;
            wv = (nti == ti) ? wl : ((ntj == tj) ? wu : wd);
            ti = nti; tj = ntj;
        }
        atomicAdd(out, loss);
    }
}

extern "C" void kernel_launch(void* const* d_in, const int* in_sizes, int n_in,
                              void* d_out, int out_size, void* d_ws, size_t ws_size,
                              hipStream_t stream) {
    const float* preds   = (const float*)d_in[0];
    const float* targs   = (const float*)d_in[1];
    const float* subcoef = (const float*)d_in[2];
    float* out = (float*)d_out;

    if (ws_size >= REQ_WS_NEW) {
        unsigned* wsu = (unsigned*)d_ws;
        init3<<<1, 256, 0, stream>>>(wsu, out);
        dtw_dp<<<BATCH * GB, 64, 0, stream>>>(preds, targs, wsu);
        dtw_bt<<<BATCH, 256, 0, stream>>>(preds, targs, subcoef,
                                          (const float*)d_ws, out);
    } else if (ws_size >= REQ_WS) {
        unsigned* dec = (unsigned*)d_ws;
        init_kernel<<<1, 1, 0, stream>>>(out);
        dtw_fused_legacy<<<BATCH, 256, 0, stream>>>(preds, targs, subcoef, dec, out);
    } else {
        unsigned* dec = (unsigned*)d_ws;
        init_kernel<<<1, 1, 0, stream>>>(out);
        dtw_fallback<<<BATCH, 256, 0, stream>>>(preds, targs, subcoef, dec, out);
    }
}